// Round 15
// baseline (461.979 us; speedup 1.0000x reference)
//
#include <hip/hip_runtime.h>
#include <cstdint>

// CapsuleLayer dynamic routing, MI355X. B=16,N=64,I=2048,D=32,E=16,R=3.
// b-logits = (sum_j v_j).u_hat -> never materialize b or u_hat in HBM;
// 3 streaming passes over W (256MB each).
// EMPIRICAL LAWS (rounds 6-14):
//  - RA budget = 256/min_waves_per_eu; live > budget => catastrophic spills.
//  - pass time scales ~linearly with 1/(W loads in flight):
//    depth 2 -> 190us (R14), depth 4 -> ~95us (R8). Latency-bound.
// THIS ROUND: spend R14's 28 spare regs (36 used / 64 budget) on load depth.
//  MODE0: 4-n W groups (8 float4 = 32 regs in flight, depth 8); live ~60.
//  MODE1: 2-n W groups (depth 4, R8's proven shape); live ~62.
//  Everything else identical to R14 (first fully spill-free round):
//  512 thr, wave owns 8 n, block owns 4 b, x in LDS (quad-broadcast),
//  waves_per_eu(4) -> budget 64, MODE1 LDS ~40KB -> 4 blocks/CU.
// Grid 1024 = 256 i-chunks x 4 b-quarters; 4 siblings per chunk are 8
// blockIdx apart (same XCD) -> W fetched once from HBM, shared via L2.
// DPP quad_perm reduce-scatter, LDS u_hat stash across in-block softmax,
// per-chunk partials + fused reduce+squash: validated machinery, unchanged.

#define B_ 16
#define N_ 64
#define I_ 2048
#define D_ 32
#define E_ 16
#define QB_ 4               // b's per block
#define EPS_ 1e-7f
#define IPER_ 8
#define NCHUNK_ 256         // i-chunks
#define GRIDP_ 1024         // pass grid = NCHUNK_ * 4 b-quarters
#define SROW_ 2048          // b-stride in s/vtot = N_*D_
#define NOUT_ 32768         // B_*N_*D_
#define PSTRIDE_ 32768      // floats per i-chunk partial
#define WN4_ 262144         // float4 stride between n planes = I_*128

template <int CTRL>
__device__ __forceinline__ float dppf(float v) {
  return __int_as_float(
      __builtin_amdgcn_update_dpp(0, __float_as_int(v), CTRL, 0xF, 0xF, true));
}
// DPP ctrl: quad_perm[1,0,3,2]=0xB1 (xor1), quad_perm[2,3,0,1]=0x4E (xor2),
// row_ror:4=0x124, row_ror:8=0x128 (rows = 16 lanes).

// u_hat for the block's 4 b's: lane ends owning b_loc=q, d=dd (u0), dd+16 (u1).
// x read from LDS (xr = &x_lds[ii][0][0]); quad-broadcast, conflict-free.
__device__ __forceinline__ void chunk4(const float4 wa0, const float4 wa1,
                                       const float* __restrict__ xr,
                                       int q, float& u0, float& u1)
{
  float p0[4], p1[4];
#pragma unroll
  for (int j = 0; j < 4; ++j) {
    const float4 xv = *(const float4*)&xr[j * E_ + 4 * q];
    p0[j] = wa0.x * xv.x + wa0.y * xv.y + wa0.z * xv.z + wa0.w * xv.w;
    p1[j] = wa1.x * xv.x + wa1.y * xv.y + wa1.z * xv.z + wa1.w * xv.w;
  }
  {
    const float r0 = p0[0] + dppf<0xB1>(p0[0]);
    const float r1 = p0[1] + dppf<0xB1>(p0[1]);
    const float r2 = p0[2] + dppf<0xB1>(p0[2]);
    const float r3 = p0[3] + dppf<0xB1>(p0[3]);
    const float sa = (q & 1) ? r1 : r0;
    const float sb = (q & 1) ? r3 : r2;
    const float a0 = sa + dppf<0x4E>(sa);
    const float a1 = sb + dppf<0x4E>(sb);
    u0 = (q & 2) ? a1 : a0;
  }
  {
    const float r0 = p1[0] + dppf<0xB1>(p1[0]);
    const float r1 = p1[1] + dppf<0xB1>(p1[1]);
    const float r2 = p1[2] + dppf<0xB1>(p1[2]);
    const float r3 = p1[3] + dppf<0xB1>(p1[3]);
    const float sa = (q & 1) ? r1 : r0;
    const float sb = (q & 1) ? r3 : r2;
    const float a0 = sa + dppf<0x4E>(sa);
    const float a1 = sb + dppf<0x4E>(sb);
    u1 = (q & 2) ? a1 : a0;
  }
}

// MODE 0: c = 1/64 (softmax of zero logits); barrier-free i-loop, ~2KB LDS,
//         W in 4-n groups (depth 8).
// MODE 1: logits = vtot . u_hat (vtot in 16 regs), softmax over n in block
//         (waves 0-3), u_hat via LDS stash, phase B LDS-only,
//         W in 2-n groups (depth 4).
template <int MODE>
__global__ __launch_bounds__(512)
__attribute__((amdgpu_waves_per_eu(4)))
void caps_pass(
    const float* __restrict__ W,     // [N][I][D][E]
    const float* __restrict__ x,     // [B][I][E]
    const float* __restrict__ vtot,  // [B][N][D]
    float* __restrict__ out,         // partials base or s (atomic)
    int use_part)
{
  const int t = threadIdx.x;   // 0..511
  const int w = t >> 6;        // wave 0..7 -> n = 8w+nn
  const int l = t & 63;
  const int q = l & 3;         // e-quarter AND b_loc
  const int dd = l >> 2;       // d (0..15); also owns d+16

  // 4 sibling quarters of an i-chunk are 8 blockIdx apart (same XCD)
  const int orig = blockIdx.x;
  const int h = (orig >> 3) & 3;                    // b-quarter
  const int ic = (orig & 7) | ((orig >> 5) << 3);   // i-chunk 0..255
  const int i0 = ic * IPER_;

  __shared__ float x_lds[IPER_ * QB_ * E_];              // 2 KB: [ii][b][e]
  __shared__ float2 u_st[(MODE == 1) ? 8 * 512 : 1];     // 32 KB (MODE1)
  __shared__ float l2[(MODE == 1) ? N_ * 17 : 1];        // logit partials
  __shared__ float c_lds[(MODE == 1) ? N_ * 5 : 1];      // c [n][b_loc]

  // preload x: 8 i's x 4 b's x 16 e = 512 = one element per thread
  {
    const int ii = t >> 6, bl = (t >> 4) & 3, e = t & 15;
    x_lds[t] = x[((size_t)(h * QB_ + bl) * I_ + (i0 + ii)) * E_ + e];
  }
  __syncthreads();

  float acc0[8], acc1[8];   // [nn]: b=h*4+q, d=dd / dd+16
#pragma unroll
  for (int nn = 0; nn < 8; ++nn) { acc0[nn] = 0.f; acc1[nn] = 0.f; }

  float vt0[8], vt1[8];
  if (MODE == 1) {
#pragma unroll
    for (int nn = 0; nn < 8; ++nn) {
      const size_t va = (size_t)(h * QB_ + q) * SROW_ +
                        (size_t)(8 * w + nn) * D_ + dd;
      vt0[nn] = vtot[va];
      vt1[nn] = vtot[va + 16];
    }
  }

  const float4* Wbase = (const float4*)W + (((size_t)(8 * w) * I_ + i0) << 7);

#pragma unroll 1
  for (int ii = 0; ii < IPER_; ++ii) {
    const float* xr = &x_lds[ii * (QB_ * E_)];

    if (MODE == 0) {
      // ---- phase A: W in 2 groups of 4 n (8 float4 = depth 8) ----
#pragma unroll 1
      for (int gg = 0; gg < 2; ++gg) {
        const float4* Wn0 = Wbase + (size_t)(4 * gg) * WN4_ + ii * 128;
        const float4* Wn1 = Wn0 + WN4_;
        const float4* Wn2 = Wn1 + WN4_;
        const float4* Wn3 = Wn2 + WN4_;
        const float4 a0 = Wn0[l], a1 = Wn0[64 + l];
        const float4 b0 = Wn1[l], b1 = Wn1[64 + l];
        const float4 c0 = Wn2[l], c1 = Wn2[64 + l];
        const float4 d0 = Wn3[l], d1 = Wn3[64 + l];
        float u0, u1;
        chunk4(a0, a1, xr, q, u0, u1);
        acc0[4 * gg + 0] += u0; acc1[4 * gg + 0] += u1;
        chunk4(b0, b1, xr, q, u0, u1);
        acc0[4 * gg + 1] += u0; acc1[4 * gg + 1] += u1;
        chunk4(c0, c1, xr, q, u0, u1);
        acc0[4 * gg + 2] += u0; acc1[4 * gg + 2] += u1;
        chunk4(d0, d1, xr, q, u0, u1);
        acc0[4 * gg + 3] += u0; acc1[4 * gg + 3] += u1;
      }
    } else {
      // ---- phase A: W in 4 groups of 2 n (4 float4 = depth 4) ----
#pragma unroll 1
      for (int g = 0; g < 4; ++g) {
        const float4* W0 = Wbase + (size_t)(2 * g) * WN4_ + ii * 128;
        const float4* W1 = W0 + WN4_;
        const float4 a0 = W0[l], a1 = W0[64 + l];
        const float4 b0 = W1[l], b1 = W1[64 + l];
#pragma unroll
        for (int s = 0; s < 2; ++s) {
          const int nn = 2 * g + s;
          float u0, u1;
          chunk4(s ? b0 : a0, s ? b1 : a1, xr, q, u0, u1);
          u_st[nn * 512 + t] = make_float2(u0, u1);
          float lp = vt0[nn] * u0 + vt1[nn] * u1;
          lp += dppf<0x124>(lp);   // + ror4
          lp += dppf<0x128>(lp);   // + ror8 -> sum over row's 4 dd
          if ((l & 12) == 0)       // one writer per (row, b_loc)
            l2[(8 * w + nn) * 17 + q * 4 + (l >> 4)] = lp;
        }
      }

      __syncthreads();
      {
        // waves 0-3: wave bw handles b_loc=bw, lane j = n
        const int bw = w, j = l;
        if (bw < QB_) {
          const int base = j * 17 + bw * 4;
          const float raw =
              l2[base] + l2[base + 1] + l2[base + 2] + l2[base + 3];
          float m = raw;
#pragma unroll
          for (int off = 32; off; off >>= 1) m = fmaxf(m, __shfl_xor(m, off));
          const float e = __expf(raw - m);
          float den = e;
#pragma unroll
          for (int off = 32; off; off >>= 1) den += __shfl_xor(den, off);
          c_lds[j * 5 + bw] = e / den;
        }
      }
      __syncthreads();
      // ---- phase B: LDS-only — stash read, apply c, accumulate ----
#pragma unroll
      for (int nn = 0; nn < 8; ++nn) {
        const float2 u = u_st[nn * 512 + t];
        const float cc = c_lds[(8 * w + nn) * 5 + q];
        acc0[nn] += cc * u.x;
        acc1[nn] += cc * u.y;
      }
    }
  }

  // store: partial slice for this i-chunk (quarters disjoint) or atomic
  const float sc = (MODE == 0) ? (1.f / 64.f) : 1.f;
  float* base = out + (use_part ? (size_t)ic * PSTRIDE_ : 0);
#pragma unroll
  for (int nn = 0; nn < 8; ++nn) {
    const int b = h * QB_ + q, n = 8 * w + nn;
    const size_t a = (size_t)b * SROW_ + (size_t)n * D_ + dd;
    if (use_part) {
      base[a] = acc0[nn] * sc;
      base[a + 16] = acc1[nn] * sc;
    } else {
      atomicAdd(&base[a], acc0[nn] * sc);
      atomicAdd(&base[a + 16], acc1[nn] * sc);
    }
  }
}

// Fused partial-reduce + squash. g = (b*64+n)*32 + d; row = 32 lanes.
// ACCMODE 0: dst[g] = squash; 1: dst[g] += squash.
template <int ACCMODE>
__global__ __launch_bounds__(256) void reduce_squash(
    const float* __restrict__ part, const float* __restrict__ s_single,
    float* __restrict__ dst, int use_part)
{
  const int g = blockIdx.x * 256 + threadIdx.x;  // 0..32767
  float sum;
  if (use_part) {
    sum = 0.f;
#pragma unroll 8
    for (int p = 0; p < NCHUNK_; ++p) sum += part[(size_t)p * PSTRIDE_ + g];
  } else {
    sum = s_single[g];
  }
  float s2 = sum * sum;  // reduce over the row's 32 lanes (xor<32 stays in row)
#pragma unroll
  for (int off = 16; off; off >>= 1) s2 += __shfl_xor(s2, off);
  const float f = s2 / ((1.f + s2) * sqrtf(s2 + EPS_));
  if (ACCMODE == 0) dst[g] = sum * f;
  else dst[g] += sum * f;
}

extern "C" void kernel_launch(void* const* d_in, const int* in_sizes, int n_in,
                              void* d_out, int out_size, void* d_ws, size_t ws_size,
                              hipStream_t stream)
{
  const float* x = (const float*)d_in[0];  // [16][2048][16]
  const float* W = (const float*)d_in[1];  // [64][2048][32][16]
  float* s = (float*)d_out;                // [b][n][d] output
  float* vtot = (float*)d_ws;              // 32768 floats
  float* part = vtot + NOUT_;              // 256 * 32768 floats if available

  const size_t need =
      ((size_t)NOUT_ + (size_t)NCHUNK_ * PSTRIDE_) * sizeof(float);
  const int use_part = (ws_size >= need) ? 1 : 0;
  float* pass_out = use_part ? part : s;
  const size_t sbytes = (size_t)NOUT_ * sizeof(float);

  // Round 1: c = 1/64 -> vtot = v0
  if (!use_part) hipMemsetAsync(s, 0, sbytes, stream);
  caps_pass<0><<<GRIDP_, 512, 0, stream>>>(W, x, vtot, pass_out, use_part);
  reduce_squash<0><<<128, 256, 0, stream>>>(part, s, vtot, use_part);

  // Round 2: logits = v0 . u_hat -> vtot += v1
  if (!use_part) hipMemsetAsync(s, 0, sbytes, stream);
  caps_pass<1><<<GRIDP_, 512, 0, stream>>>(W, x, vtot, pass_out, use_part);
  reduce_squash<1><<<128, 256, 0, stream>>>(part, s, vtot, use_part);

  // Round 3: logits = (v0+v1) . u_hat -> final squash into d_out
  if (!use_part) hipMemsetAsync(s, 0, sbytes, stream);
  caps_pass<1><<<GRIDP_, 512, 0, stream>>>(W, x, vtot, pass_out, use_part);
  reduce_squash<0><<<128, 256, 0, stream>>>(part, s, s, use_part);
}

// Round 16
// 414.746 us; speedup vs baseline: 1.1139x; 1.1139x over previous
//
#include <hip/hip_runtime.h>
#include <cstdint>

// CapsuleLayer dynamic routing, MI355X. B=16,N=64,I=2048,D=32,E=16,R=3.
// b-logits = (sum_j v_j).u_hat -> never materialize b or u_hat in HBM;
// 3 streaming passes over W (256MB each).
// ATTRIBUTE SEMANTICS (measured, rounds 6-15): the scheduler targets the MAX
// waves/EU term -> VGPR target = 256/max: (2,2)->108, (2,4)->76, (4,4)->64,
// (4)/(8)->32-36 (loads sunk, ILP destroyed). (4,4) is the only setting that
// honestly targets 64 and HOLDS multi-load depth (R8: VGPR 64, depth 4).
// OCCUPANCY: R8 was grid-capped (512 blocks = 2/CU = 16 waves/CU = 50%).
// THIS ROUND: quarter-blocks fix the grid cap: 512 thr (8 waves, wave owns
// 8 n), block owns 4 b; grid 1024 = 4 blocks/CU; MODE1 LDS 39.6KB -> 4
// blocks fit; VGPR<=64 tier allows 32 waves/CU. Both modes: W in 2-n groups
// (depth 4, live ~48-60 <= 64). Model: time ~ C/(depth x waves):
// R8 = d4 x 16w -> 95us; this = d4 x 32w -> ~50us/pass.
// 4 sibling quarters per i-chunk are 8 blockIdx apart (same XCD) -> W
// fetched once from HBM, shared via that XCD's L2.
// DPP quad_perm reduce-scatter, LDS u_hat stash across in-block softmax,
// per-chunk partials + fused reduce+squash: validated machinery, unchanged.

#define B_ 16
#define N_ 64
#define I_ 2048
#define D_ 32
#define E_ 16
#define QB_ 4               // b's per block
#define EPS_ 1e-7f
#define IPER_ 8
#define NCHUNK_ 256         // i-chunks
#define GRIDP_ 1024         // pass grid = NCHUNK_ * 4 b-quarters
#define SROW_ 2048          // b-stride in s/vtot = N_*D_
#define NOUT_ 32768         // B_*N_*D_
#define PSTRIDE_ 32768      // floats per i-chunk partial
#define WN4_ 262144         // float4 stride between n planes = I_*128

template <int CTRL>
__device__ __forceinline__ float dppf(float v) {
  return __int_as_float(
      __builtin_amdgcn_update_dpp(0, __float_as_int(v), CTRL, 0xF, 0xF, true));
}
// DPP ctrl: quad_perm[1,0,3,2]=0xB1 (xor1), quad_perm[2,3,0,1]=0x4E (xor2),
// row_ror:4=0x124, row_ror:8=0x128 (rows = 16 lanes).

// u_hat for the block's 4 b's: lane ends owning b_loc=q, d=dd (u0), dd+16 (u1).
// x read from LDS (xr = &x_lds[ii][0][0]); quad-broadcast, conflict-free.
__device__ __forceinline__ void chunk4(const float4 wa0, const float4 wa1,
                                       const float* __restrict__ xr,
                                       int q, float& u0, float& u1)
{
  float p0[4], p1[4];
#pragma unroll
  for (int j = 0; j < 4; ++j) {
    const float4 xv = *(const float4*)&xr[j * E_ + 4 * q];
    p0[j] = wa0.x * xv.x + wa0.y * xv.y + wa0.z * xv.z + wa0.w * xv.w;
    p1[j] = wa1.x * xv.x + wa1.y * xv.y + wa1.z * xv.z + wa1.w * xv.w;
  }
  {
    const float r0 = p0[0] + dppf<0xB1>(p0[0]);
    const float r1 = p0[1] + dppf<0xB1>(p0[1]);
    const float r2 = p0[2] + dppf<0xB1>(p0[2]);
    const float r3 = p0[3] + dppf<0xB1>(p0[3]);
    const float sa = (q & 1) ? r1 : r0;
    const float sb = (q & 1) ? r3 : r2;
    const float a0 = sa + dppf<0x4E>(sa);
    const float a1 = sb + dppf<0x4E>(sb);
    u0 = (q & 2) ? a1 : a0;
  }
  {
    const float r0 = p1[0] + dppf<0xB1>(p1[0]);
    const float r1 = p1[1] + dppf<0xB1>(p1[1]);
    const float r2 = p1[2] + dppf<0xB1>(p1[2]);
    const float r3 = p1[3] + dppf<0xB1>(p1[3]);
    const float sa = (q & 1) ? r1 : r0;
    const float sb = (q & 1) ? r3 : r2;
    const float a0 = sa + dppf<0x4E>(sa);
    const float a1 = sb + dppf<0x4E>(sb);
    u1 = (q & 2) ? a1 : a0;
  }
}

// MODE 0: c = 1/64 (softmax of zero logits); barrier-free i-loop, ~2KB LDS.
// MODE 1: logits = vtot . u_hat (vtot in 16 regs), softmax over n in block
//         (waves 0-3), u_hat via LDS stash, phase B LDS-only.
// Both: W in 4 groups of 2 n per i (4 float4 = depth 4, R8's proven depth).
template <int MODE>
__global__ __launch_bounds__(512)
__attribute__((amdgpu_waves_per_eu(4, 4)))
void caps_pass(
    const float* __restrict__ W,     // [N][I][D][E]
    const float* __restrict__ x,     // [B][I][E]
    const float* __restrict__ vtot,  // [B][N][D]
    float* __restrict__ out,         // partials base or s (atomic)
    int use_part)
{
  const int t = threadIdx.x;   // 0..511
  const int w = t >> 6;        // wave 0..7 -> n = 8w+nn
  const int l = t & 63;
  const int q = l & 3;         // e-quarter AND b_loc
  const int dd = l >> 2;       // d (0..15); also owns d+16

  // 4 sibling quarters of an i-chunk are 8 blockIdx apart (same XCD)
  const int orig = blockIdx.x;
  const int h = (orig >> 3) & 3;                    // b-quarter
  const int ic = (orig & 7) | ((orig >> 5) << 3);   // i-chunk 0..255
  const int i0 = ic * IPER_;

  __shared__ float x_lds[IPER_ * QB_ * E_];              // 2 KB: [ii][b][e]
  __shared__ float2 u_st[(MODE == 1) ? 8 * 512 : 1];     // 32 KB (MODE1)
  __shared__ float l2[(MODE == 1) ? N_ * 17 : 1];        // logit partials
  __shared__ float c_lds[(MODE == 1) ? N_ * 5 : 1];      // c [n][b_loc]

  // preload x: 8 i's x 4 b's x 16 e = 512 = one element per thread
  {
    const int ii = t >> 6, bl = (t >> 4) & 3, e = t & 15;
    x_lds[t] = x[((size_t)(h * QB_ + bl) * I_ + (i0 + ii)) * E_ + e];
  }
  __syncthreads();

  float acc0[8], acc1[8];   // [nn]: b=h*4+q, d=dd / dd+16
#pragma unroll
  for (int nn = 0; nn < 8; ++nn) { acc0[nn] = 0.f; acc1[nn] = 0.f; }

  float vt0[8], vt1[8];
  if (MODE == 1) {
#pragma unroll
    for (int nn = 0; nn < 8; ++nn) {
      const size_t va = (size_t)(h * QB_ + q) * SROW_ +
                        (size_t)(8 * w + nn) * D_ + dd;
      vt0[nn] = vtot[va];
      vt1[nn] = vtot[va + 16];
    }
  }

  const float4* Wbase = (const float4*)W + (((size_t)(8 * w) * I_ + i0) << 7);

#pragma unroll 1
  for (int ii = 0; ii < IPER_; ++ii) {
    const float* xr = &x_lds[ii * (QB_ * E_)];

    // ---- phase A: W in 4 groups of 2 n (4 float4 = depth 4) ----
#pragma unroll 1
    for (int g = 0; g < 4; ++g) {
      const float4* W0 = Wbase + (size_t)(2 * g) * WN4_ + ii * 128;
      const float4* W1 = W0 + WN4_;
      const float4 a0 = W0[l], a1 = W0[64 + l];
      const float4 b0 = W1[l], b1 = W1[64 + l];
#pragma unroll
      for (int s = 0; s < 2; ++s) {
        const int nn = 2 * g + s;
        float u0, u1;
        chunk4(s ? b0 : a0, s ? b1 : a1, xr, q, u0, u1);
        if (MODE == 0) {
          acc0[nn] += u0;
          acc1[nn] += u1;
        } else {
          u_st[nn * 512 + t] = make_float2(u0, u1);
          float lp = vt0[nn] * u0 + vt1[nn] * u1;
          lp += dppf<0x124>(lp);   // + ror4
          lp += dppf<0x128>(lp);   // + ror8 -> sum over row's 4 dd
          if ((l & 12) == 0)       // one writer per (row, b_loc)
            l2[(8 * w + nn) * 17 + q * 4 + (l >> 4)] = lp;
        }
      }
    }

    if (MODE == 1) {
      __syncthreads();
      {
        // waves 0-3: wave bw handles b_loc=bw, lane j = n
        const int bw = w, j = l;
        if (bw < QB_) {
          const int base = j * 17 + bw * 4;
          const float raw =
              l2[base] + l2[base + 1] + l2[base + 2] + l2[base + 3];
          float m = raw;
#pragma unroll
          for (int off = 32; off; off >>= 1) m = fmaxf(m, __shfl_xor(m, off));
          const float e = __expf(raw - m);
          float den = e;
#pragma unroll
          for (int off = 32; off; off >>= 1) den += __shfl_xor(den, off);
          c_lds[j * 5 + bw] = e / den;
        }
      }
      __syncthreads();
      // ---- phase B: LDS-only — stash read, apply c, accumulate ----
#pragma unroll
      for (int nn = 0; nn < 8; ++nn) {
        const float2 u = u_st[nn * 512 + t];
        const float cc = c_lds[(8 * w + nn) * 5 + q];
        acc0[nn] += cc * u.x;
        acc1[nn] += cc * u.y;
      }
    }
  }

  // store: partial slice for this i-chunk (quarters disjoint) or atomic
  const float sc = (MODE == 0) ? (1.f / 64.f) : 1.f;
  float* base = out + (use_part ? (size_t)ic * PSTRIDE_ : 0);
#pragma unroll
  for (int nn = 0; nn < 8; ++nn) {
    const int b = h * QB_ + q, n = 8 * w + nn;
    const size_t a = (size_t)b * SROW_ + (size_t)n * D_ + dd;
    if (use_part) {
      base[a] = acc0[nn] * sc;
      base[a + 16] = acc1[nn] * sc;
    } else {
      atomicAdd(&base[a], acc0[nn] * sc);
      atomicAdd(&base[a + 16], acc1[nn] * sc);
    }
  }
}

// Fused partial-reduce + squash. g = (b*64+n)*32 + d; row = 32 lanes.
// ACCMODE 0: dst[g] = squash; 1: dst[g] += squash.
template <int ACCMODE>
__global__ __launch_bounds__(256) void reduce_squash(
    const float* __restrict__ part, const float* __restrict__ s_single,
    float* __restrict__ dst, int use_part)
{
  const int g = blockIdx.x * 256 + threadIdx.x;  // 0..32767
  float sum;
  if (use_part) {
    sum = 0.f;
#pragma unroll 8
    for (int p = 0; p < NCHUNK_; ++p) sum += part[(size_t)p * PSTRIDE_ + g];
  } else {
    sum = s_single[g];
  }
  float s2 = sum * sum;  // reduce over the row's 32 lanes (xor<32 stays in row)
#pragma unroll
  for (int off = 16; off; off >>= 1) s2 += __shfl_xor(s2, off);
  const float f = s2 / ((1.f + s2) * sqrtf(s2 + EPS_));
  if (ACCMODE == 0) dst[g] = sum * f;
  else dst[g] += sum * f;
}

extern "C" void kernel_launch(void* const* d_in, const int* in_sizes, int n_in,
                              void* d_out, int out_size, void* d_ws, size_t ws_size,
                              hipStream_t stream)
{
  const float* x = (const float*)d_in[0];  // [16][2048][16]
  const float* W = (const float*)d_in[1];  // [64][2048][32][16]
  float* s = (float*)d_out;                // [b][n][d] output
  float* vtot = (float*)d_ws;              // 32768 floats
  float* part = vtot + NOUT_;              // 256 * 32768 floats if available

  const size_t need =
      ((size_t)NOUT_ + (size_t)NCHUNK_ * PSTRIDE_) * sizeof(float);
  const int use_part = (ws_size >= need) ? 1 : 0;
  float* pass_out = use_part ? part : s;
  const size_t sbytes = (size_t)NOUT_ * sizeof(float);

  // Round 1: c = 1/64 -> vtot = v0
  if (!use_part) hipMemsetAsync(s, 0, sbytes, stream);
  caps_pass<0><<<GRIDP_, 512, 0, stream>>>(W, x, vtot, pass_out, use_part);
  reduce_squash<0><<<128, 256, 0, stream>>>(part, s, vtot, use_part);

  // Round 2: logits = v0 . u_hat -> vtot += v1
  if (!use_part) hipMemsetAsync(s, 0, sbytes, stream);
  caps_pass<1><<<GRIDP_, 512, 0, stream>>>(W, x, vtot, pass_out, use_part);
  reduce_squash<1><<<128, 256, 0, stream>>>(part, s, vtot, use_part);

  // Round 3: logits = (v0+v1) . u_hat -> final squash into d_out
  if (!use_part) hipMemsetAsync(s, 0, sbytes, stream);
  caps_pass<1><<<GRIDP_, 512, 0, stream>>>(W, x, vtot, pass_out, use_part);
  reduce_squash<0><<<128, 256, 0, stream>>>(part, s, s, use_part);
}